// Round 10
// baseline (457.393 us; speedup 1.0000x reference)
//
#include <hip/hip_runtime.h>
#include <hip/hip_bf16.h>

#define PED   512
#define HDIM  64
#define EDIM  32
#define NPAIR (PED * PED)          // 262144 rows
#define GATES 256                  // 4*H
#define WF_ELEMS (48 * 64 * 8)     // W frags: [slot][lane][j], slot=(gate_tile*3+ks)

typedef __attribute__((ext_vector_type(8))) __bf16 bf16x8;
typedef __attribute__((ext_vector_type(4))) float  floatx4;

__device__ __forceinline__ float sigmoidf_fast(float x) {
    return __builtin_amdgcn_rcpf(1.0f + __expf(-x));
}
__device__ __forceinline__ float tanhf_fast(float x) {
    return fmaf(2.0f, __builtin_amdgcn_rcpf(1.0f + __expf(-2.0f * x)), -1.0f);
}

// ---- prep: weights -> bf16 MFMA A-fragments, LANE-CONTIGUOUS slot layout ----
// Wf[((gate_tile*3 + ks)*64 + lane)*8 + j] = W[gate_tile*16 + (lane&15)]
//                                             [ks*32 + (lane>>4)*8 + j]
__global__ void sra_prep(const float* __restrict__ W_ih, const float* __restrict__ W_hh,
                         const float* __restrict__ b_ih, const float* __restrict__ b_hh,
                         __bf16* __restrict__ Wf, float* __restrict__ bsum)
{
    int tid = blockIdx.x * 256 + threadIdx.x;
    if (tid < WF_ELEMS) {
        int j    = tid & 7;
        int lane = (tid >> 3) & 63;
        int s    = tid >> 9;                    // slot 0..47
        int nt   = s / 3;                       // gate tile 0..15
        int ks   = s - nt * 3;                  // k-step 0..2
        int n = nt * 16 + (lane & 15);          // gate index
        int k = ks * 32 + (lane >> 4) * 8 + j;  // k index
        float w = (k < EDIM) ? W_ih[n * EDIM + k] : W_hh[n * HDIM + (k - EDIM)];
        Wf[tid] = (__bf16)w;
    }
    if (tid < GATES) bsum[tid] = b_ih[tid] + b_hh[tid];
}

// ---- main: NO LDS, NO barrier. W fragments read directly from global
// (lane-contiguous layout -> 16 lines/instr, fully coalesced; the 48KB table
// is L1/L2-hot for every wave on the CU). R9 showed block-convoy stall
// (~75% of wave lifetime unaccounted by any pipe) caused by the 512-thread
// stage+syncthreads structure; removing it lets waves free-run.
// 256-thread blocks -> 64-row span (small-span quadrant: R6/R7/R8 failures
// were all span>=256 or strided). Per-wave structure otherwise R9-identical.
__global__ __launch_bounds__(256, 6)
void sra_main(const float* __restrict__ corr,
              const float* __restrict__ ht,
              const float* __restrict__ ct,
              const int*   __restrict__ nei,
              const float* __restrict__ W_emb,
              const float* __restrict__ b_emb,
              const __bf16* __restrict__ Wf,
              const float* __restrict__ bsumg,
              float* __restrict__ h_out,
              float* __restrict__ c_out)
{
    const int tid  = threadIdx.x;
    const int wave = tid >> 6;
    const int lane = tid & 63;
    const int lo   = lane & 15;
    const int qu   = lane >> 4;

    const int tile = blockIdx.x * 4 + wave;
    const int row  = tile * 16 + lo;                 // this lane's pair-row
    const size_t rowoff = (size_t)row * HDIM;

    // ---- ALL per-row global reads issued up front (max MLP) ----
    const float2 xy = *(const float2*)(corr + (size_t)row * 2);
    const floatx4 h0a = *(const floatx4*)(ht + rowoff + qu * 8);
    const floatx4 h0b = *(const floatx4*)(ht + rowoff + qu * 8 + 4);
    const floatx4 h1a = *(const floatx4*)(ht + rowoff + 32 + qu * 8);
    const floatx4 h1b = *(const floatx4*)(ht + rowoff + 32 + qu * 8 + 4);
    floatx4 cold0 = *(const floatx4*)(ct + rowoff +      qu * 4);
    floatx4 cold1 = *(const floatx4*)(ct + rowoff + 16 + qu * 4);
    floatx4 cold2 = *(const floatx4*)(ct + rowoff + 32 + qu * 4);
    floatx4 cold3 = *(const floatx4*)(ct + rowoff + 48 + qu * 4);
    floatx4 hold0 = *(const floatx4*)(ht + rowoff +      qu * 4);
    floatx4 hold1 = *(const floatx4*)(ht + rowoff + 16 + qu * 4);
    floatx4 hold2 = *(const floatx4*)(ht + rowoff + 32 + qu * 4);
    floatx4 hold3 = *(const floatx4*)(ht + rowoff + 48 + qu * 4);
    const bool msk = nei[row] > 0;                   // lane-uniform mask

    // ---- x B-frag (k 0..31): embedding + ReLU, in-register ----
    bf16x8 b0;
#pragma unroll
    for (int j = 0; j < 8; ++j) {
        const int e = qu * 8 + j;
        float v = fmaf(xy.x, W_emb[e * 2 + 0], fmaf(xy.y, W_emb[e * 2 + 1], b_emb[e]));
        b0[j] = (__bf16)fmaxf(v, 0.0f);
    }
    // ---- h B-frags (k 32..95) ----
    bf16x8 b1, b2;
#pragma unroll
    for (int j = 0; j < 4; ++j) {
        b1[j]     = (__bf16)h0a[j];
        b1[j + 4] = (__bf16)h0b[j];
        b2[j]     = (__bf16)h1a[j];
        b2[j + 4] = (__bf16)h1b[j];
    }

    // pin hoisted epilogue operands in VGPRs (anti-remat; R4's failure mode)
    asm volatile("" : "+v"(cold0), "+v"(cold1), "+v"(cold2), "+v"(cold3),
                      "+v"(hold0), "+v"(hold1), "+v"(hold2), "+v"(hold3));

    const bf16x8* wp = (const bf16x8*)Wf;            // [slot][lane] 16B frags

    const floatx4 colds[4] = {cold0, cold1, cold2, cold3};
    const floatx4 holds[4] = {hold0, hold1, hold2, hold3};

    // ---- 4 gate-quad groups: 12 coalesced global W-loads + 12 MFMA + VALU ----
#pragma unroll
    for (int g = 0; g < 4; ++g) {
        const int kb = g * 16 + qu * 4;              // gate sub-index [0,64)

        const floatx4 cold = colds[g];
        const floatx4 hold = holds[g];
        const floatx4 bi4  = *(const floatx4*)(bsumg + kb);        // L1-hot
        const floatx4 bf4  = *(const floatx4*)(bsumg + 64 + kb);
        const floatx4 bg4  = *(const floatx4*)(bsumg + 128 + kb);
        const floatx4 bo4  = *(const floatx4*)(bsumg + 192 + kb);

        const bf16x8 wi0 = wp[((g     ) * 3 + 0) * 64 + lane];
        const bf16x8 wi1 = wp[((g     ) * 3 + 1) * 64 + lane];
        const bf16x8 wi2 = wp[((g     ) * 3 + 2) * 64 + lane];
        const bf16x8 wf0 = wp[((g +  4) * 3 + 0) * 64 + lane];
        const bf16x8 wf1 = wp[((g +  4) * 3 + 1) * 64 + lane];
        const bf16x8 wf2 = wp[((g +  4) * 3 + 2) * 64 + lane];
        const bf16x8 wg0 = wp[((g +  8) * 3 + 0) * 64 + lane];
        const bf16x8 wg1 = wp[((g +  8) * 3 + 1) * 64 + lane];
        const bf16x8 wg2 = wp[((g +  8) * 3 + 2) * 64 + lane];
        const bf16x8 wo0 = wp[((g + 12) * 3 + 0) * 64 + lane];
        const bf16x8 wo1 = wp[((g + 12) * 3 + 1) * 64 + lane];
        const bf16x8 wo2 = wp[((g + 12) * 3 + 2) * 64 + lane];

        const floatx4 z = {0.f, 0.f, 0.f, 0.f};
        floatx4 ai = __builtin_amdgcn_mfma_f32_16x16x32_bf16(wi0, b0, z, 0, 0, 0);
        floatx4 af = __builtin_amdgcn_mfma_f32_16x16x32_bf16(wf0, b0, z, 0, 0, 0);
        floatx4 ag = __builtin_amdgcn_mfma_f32_16x16x32_bf16(wg0, b0, z, 0, 0, 0);
        floatx4 ao = __builtin_amdgcn_mfma_f32_16x16x32_bf16(wo0, b0, z, 0, 0, 0);
        ai = __builtin_amdgcn_mfma_f32_16x16x32_bf16(wi1, b1, ai, 0, 0, 0);
        af = __builtin_amdgcn_mfma_f32_16x16x32_bf16(wf1, b1, af, 0, 0, 0);
        ag = __builtin_amdgcn_mfma_f32_16x16x32_bf16(wg1, b1, ag, 0, 0, 0);
        ao = __builtin_amdgcn_mfma_f32_16x16x32_bf16(wo1, b1, ao, 0, 0, 0);
        ai = __builtin_amdgcn_mfma_f32_16x16x32_bf16(wi2, b2, ai, 0, 0, 0);
        af = __builtin_amdgcn_mfma_f32_16x16x32_bf16(wf2, b2, af, 0, 0, 0);
        ag = __builtin_amdgcn_mfma_f32_16x16x32_bf16(wg2, b2, ag, 0, 0, 0);
        ao = __builtin_amdgcn_mfma_f32_16x16x32_bf16(wo2, b2, ao, 0, 0, 0);

        floatx4 cn4, hn4;
#pragma unroll
        for (int r = 0; r < 4; ++r) {
            const float iv = sigmoidf_fast(ai[r] + bi4[r]);
            const float fv = sigmoidf_fast(af[r] + bf4[r]);
            const float gv = tanhf_fast(ag[r] + bg4[r]);
            const float ov = sigmoidf_fast(ao[r] + bo4[r]);
            const float cn = fv * cold[r] + iv * gv;
            const float hn = ov * tanhf_fast(cn);
            cn4[r] = msk ? cn : cold[r];
            hn4[r] = msk ? hn : hold[r];
        }
        *(floatx4*)(c_out + rowoff + kb) = cn4;
        *(floatx4*)(h_out + rowoff + kb) = hn4;
    }
}

extern "C" void kernel_launch(void* const* d_in, const int* in_sizes, int n_in,
                              void* d_out, int out_size, void* d_ws, size_t ws_size,
                              hipStream_t stream) {
    const float* corr  = (const float*)d_in[0];
    const float* ht    = (const float*)d_in[1];
    const float* ct    = (const float*)d_in[2];
    const int*   nei   = (const int*)  d_in[3];
    const float* W_emb = (const float*)d_in[4];
    const float* b_emb = (const float*)d_in[5];
    const float* W_ih  = (const float*)d_in[6];
    const float* W_hh  = (const float*)d_in[7];
    const float* b_ih  = (const float*)d_in[8];
    const float* b_hh  = (const float*)d_in[9];

    __bf16* Wf   = (__bf16*)d_ws;                        // 49152 B
    float*  bsum = (float*)((char*)d_ws + WF_ELEMS * 2); // 1024 B

    float* hout = (float*)d_out;
    float* cout = hout + (size_t)NPAIR * HDIM;

    hipLaunchKernelGGL(sra_prep, dim3(96), dim3(256), 0, stream,
                       W_ih, W_hh, b_ih, b_hh, Wf, bsum);
    hipLaunchKernelGGL(sra_main, dim3(NPAIR / 64), dim3(256), 0, stream,
                       corr, ht, ct, nei, W_emb, b_emb, Wf, bsum, hout, cout);
}